// Round 1
// baseline (1476.208 us; speedup 1.0000x reference)
//
#include <hip/hip_runtime.h>
#include <hip/hip_bf16.h>

#define NN 100000
#define NE 1600000
#define NG 1000
#define SS 32
#define HH 128
#define ROUNDS 5

constexpr float NEG = 0.01f;
constexpr float EPS = 1e-5f;

// ---- workspace layout (float-slot offsets) ----
constexpr long OFF_STATE = 0;                          // N*S fp32
constexpr long OFF_GS    = OFF_STATE + (long)NN * SS;  // G*S
constexpr long OFF_W1T   = OFF_GS + (long)NG * SS;     // 128*33 (transposed, fallback)
constexpr long OFF_B1    = OFF_W1T + HH * 33;
constexpr long OFF_G1    = OFF_B1 + HH;
constexpr long OFF_BE1   = OFF_G1 + HH;
constexpr long OFF_W2    = OFF_BE1 + HH;               // 128*32 row-major (fallback)
constexpr long OFF_B2    = OFF_W2 + HH * SS;
constexpr long OFF_G2    = OFF_B2 + SS;
constexpr long OFF_BE2   = OFF_G2 + SS;
constexpr long OFF_WO1   = OFF_BE2 + SS;               // 32*128 row-major
constexpr long OFF_BO1   = OFF_WO1 + SS * HH;
constexpr long OFF_GO    = OFF_BO1 + HH;
constexpr long OFF_BEO   = OFF_GO + HH;
constexpr long OFF_WO2   = OFF_BEO + HH;               // 128*2
constexpr long OFF_BO2   = OFF_WO2 + HH * 2;
constexpr long OFF_W1L   = OFF_BO2 + 2;                // 128 f32: W1 row 32 (ec weights)
constexpr long OFF_WSC   = OFF_W1L + HH;               // 2 f32: sum(w1l), sum(w1l^2)
// MFMA B-fragment tables (bf16 pairs, one u32 word per 2 k-elems):
// W1B: [t(8)][lane(64)][q(4)] for k<32 (node kernel). W2F: [ks(4)][t2(2)][lane(64)][q(4)].
constexpr long OFF_W1B   = OFF_WSC + 2;                // 2048 u32 words
constexpr long OFF_W2F   = OFF_W1B + 2048;             // 2048 u32 words
constexpr long W_END     = OFF_W2F + 2048;
// gather-path regions. OFF_DELTA (fallback) ALIASES F_Z — safe: paths are
// mutually exclusive and prep zeros DELTA; z is fully rewritten before reads.
constexpr long OFF_DELTA = W_END;                      // N*S fp32 (fallback only)
constexpr long F_Z      = W_END;                       // N*128 bf16 = N*64 u32 slots
constexpr long F_ZST    = F_Z + (long)NN * 64;         // N float4 {sumz, sqz, dzw, 0}
constexpr long F_DEG    = F_ZST + (long)NN * 4;        // N int
constexpr long F_START  = F_DEG + NN;                  // N+1 int (padded to N+4)
constexpr long F_CURSOR = F_START + NN + 4;            // N int
constexpr long F_BSUM   = F_CURSOR + NN;               // 512 int
constexpr long F_ELIST  = F_BSUM + 512;                // E int (CSR pos -> edge)
constexpr long F_GDEG   = F_ELIST + NE;                // G int
constexpr long F_GSTART = F_GDEG + NG;                 // G+1 int (padded to G+4)
constexpr long F_GCUR   = F_GSTART + NG + 4;           // G int
constexpr long F_GLIST  = F_GCUR + NG;                 // N int (nodes sorted by graph)
constexpr long F_USRC   = F_GLIST + NN;                // E int: nfrom in CSR order
constexpr long F_ECP    = F_USRC + NE;                 // E f32: ec in CSR order
constexpr long F_MSG    = F_ECP + NE;                  // E*S bf16 = E*16 u32 slots
constexpr long WS_TOTAL = F_MSG + (long)NE * SS / 2;
constexpr long WS_FALLBACK = W_END + (long)NN * SS;
constexpr int  NBLK_N  = (NN + 255) / 256;             // 391

typedef float f32x4 __attribute__((ext_vector_type(4)));
typedef unsigned int u32x4 __attribute__((ext_vector_type(4)));
typedef short s16x8 __attribute__((ext_vector_type(8)));

__device__ __forceinline__ s16x8 as_s16x8(u32x4 u) {
    union { u32x4 a; s16x8 b; } c; c.a = u; return c.b;
}
__device__ __forceinline__ float bf2f(unsigned short u) {
    union { unsigned int i; float f; } v;
    v.i = ((unsigned int)u) << 16;
    return v.f;
}
__device__ __forceinline__ float lo_bf(unsigned int p) {
    union { unsigned int i; float f; } v; v.i = p << 16; return v.f;
}
__device__ __forceinline__ float hi_bf(unsigned int p) {
    union { unsigned int i; float f; } v; v.i = p & 0xFFFF0000u; return v.f;
}
__device__ __forceinline__ unsigned short f2bf(float f) {
    union { float f; unsigned int u; } x; x.f = f;
    return (unsigned short)((x.u + 0x7FFFu + ((x.u >> 16) & 1u)) >> 16);
}
__device__ __forceinline__ unsigned int pack_bf2(float a, float b) {
    return (unsigned int)f2bf(a) | ((unsigned int)f2bf(b) << 16);
}
#if defined(__has_builtin)
#if __has_builtin(__builtin_amdgcn_cvt_pk_bf16_f32)
#define HAVE_CVT_PK_BF16 1
#endif
#endif
__device__ __forceinline__ unsigned int cvt2bf(float a, float b) {
#ifdef HAVE_CVT_PK_BF16
    auto r = __builtin_amdgcn_cvt_pk_bf16_f32(a, b);   // lo=a, hi=b
    unsigned int u; __builtin_memcpy(&u, &r, 4); return u;
#else
    return pack_bf2(a, b);
#endif
}
// DPP row-rotate add reduction over a 16-lane row (pure VALU, no LDS pipe).
template <int CTRL>
__device__ __forceinline__ float ror_add(float x) {
    int v = __builtin_amdgcn_update_dpp(0, __float_as_int(x), CTRL, 0xF, 0xF, true);
    return x + __int_as_float(v);
}
__device__ __forceinline__ float row_reduce16(float x) {
    x = ror_add<0x121>(x);
    x = ror_add<0x122>(x);
    x = ror_add<0x124>(x);
    x = ror_add<0x128>(x);
    return x;
}
// Dtype self-detection: g1 is all-1.0. fp32 -> low16 of first u32 == 0.
__device__ __forceinline__ int is_bf16(const void* g1raw) {
    return (((const unsigned int*)g1raw)[0] & 0xFFFFu) != 0u;
}
__device__ __forceinline__ float ldf(const void* p, long idx, int bf) {
    return bf ? bf2f(((const unsigned short*)p)[idx]) : ((const float*)p)[idx];
}

// Zero state/gs/deg/gdeg/delta-alias; fp32 weight tables; MFMA fragment tables.
__global__ void prep_kernel(
    const void* __restrict__ W1,  const void* __restrict__ b1,
    const void* __restrict__ g1,  const void* __restrict__ be1,
    const void* __restrict__ W2,  const void* __restrict__ b2,
    const void* __restrict__ g2,  const void* __restrict__ be2,
    const void* __restrict__ Wo1, const void* __restrict__ bo1,
    const void* __restrict__ go,  const void* __restrict__ beo,
    const void* __restrict__ Wo2, const void* __restrict__ bo2,
    float* __restrict__ ws)
{
    const int bf = is_bf16(g1);
    long idx = (long)blockIdx.x * blockDim.x + threadIdx.x;
    if (idx < (long)NN * SS) { ws[OFF_STATE + idx] = 0.f; ws[OFF_DELTA + idx] = 0.f; }
    if (idx < (long)NG * SS) ws[OFF_GS + idx] = 0.f;
    if (idx < NN) ((int*)(ws + F_DEG))[idx] = 0;
    if (idx < NG) ((int*)(ws + F_GDEG))[idx] = 0;
    if (idx < 33 * HH) {
        int i = (int)(idx / HH), k = (int)(idx % HH);
        ws[OFF_W1T + (long)k * 33 + i] = ldf(W1, idx, bf);
    }
    if (idx < HH) {
        ws[OFF_B1  + idx] = ldf(b1,  idx, bf);
        ws[OFF_G1  + idx] = ldf(g1,  idx, bf);
        ws[OFF_BE1 + idx] = ldf(be1, idx, bf);
        ws[OFF_BO1 + idx] = ldf(bo1, idx, bf);
        ws[OFF_GO  + idx] = ldf(go,  idx, bf);
        ws[OFF_BEO + idx] = ldf(beo, idx, bf);
        ws[OFF_W1L + idx] = ldf(W1, (long)32 * HH + idx, bf);   // W1 last row (ec)
    }
    if (idx == 0) {
        float sw = 0.f, sq = 0.f;
        for (int i = 0; i < HH; i++) {
            float w = ldf(W1, (long)32 * HH + i, bf);
            sw += w; sq = fmaf(w, w, sq);
        }
        ws[OFF_WSC] = sw; ws[OFF_WSC + 1] = sq;
    }
    if (idx < HH * SS) ws[OFF_W2 + idx] = ldf(W2, idx, bf);
    if (idx < SS) {
        ws[OFF_B2  + idx] = ldf(b2,  idx, bf);
        ws[OFF_G2  + idx] = ldf(g2,  idx, bf);
        ws[OFF_BE2 + idx] = ldf(be2, idx, bf);
    }
    if (idx < SS * HH) ws[OFF_WO1 + idx] = ldf(Wo1, idx, bf);
    if (idx < HH * 2)  ws[OFF_WO2 + idx] = ldf(Wo2, idx, bf);
    if (idx < 2)       ws[OFF_BO2 + idx] = ldf(bo2, idx, bf);
    // W1B: B-frag for z = state*W1[:32]. word w = (t*64+L)*4+q holds
    // k = (L>>4)*8+2q (+1), n = t*16+(L&15).
    if (idx < 2048) {
        int w = (int)idx;
        int qq = w & 3, L = (w >> 2) & 63, t = (int)(w >> 8);
        int k0 = (L >> 4) * 8 + 2 * qq;
        int n  = t * 16 + (L & 15);
        ((unsigned int*)(ws + OFF_W1B))[w] =
            pack_bf2(ldf(W1, (long)k0 * HH + n, bf), ldf(W1, (long)(k0 + 1) * HH + n, bf));
    }
    // W2F: word w = ((ks*2+t2)*64+L)*4+q ; k = ks*32+(L>>4)*8+2q, n = t2*16+(L&15)
    // (serves as either B-frag [n][k] or, operand-swapped, A-frag [m=n][k] of W2^T)
    if (idx < 2048) {
        int w = (int)idx;
        int qq = w & 3, L = (w >> 2) & 63, t2 = (w >> 8) & 1, ks = (int)(w >> 9);
        int k0 = ks * 32 + (L >> 4) * 8 + 2 * qq;
        int n  = t2 * 16 + (L & 15);
        float v0 = ldf(W2, (long)k0 * SS + n, bf);
        float v1 = ldf(W2, (long)(k0 + 1) * SS + n, bf);
        ((unsigned int*)(ws + OFF_W2F))[w] = pack_bf2(v0, v1);
    }
}

// ---------------- CSR builds (once per launch) ----------------
__global__ void hist_kernel(const int* __restrict__ nto, float* ws) {
    int e = blockIdx.x * 256 + threadIdx.x;
    if (e < NE) atomicAdd(&((int*)(ws + F_DEG))[nto[e]], 1);
}

__global__ void scan1_kernel(float* ws) {
    __shared__ int sh[256];
    int* deg   = (int*)(ws + F_DEG);
    int* start = (int*)(ws + F_START);
    int* bsum  = (int*)(ws + F_BSUM);
    int i = blockIdx.x * 256 + threadIdx.x;
    int x = (i < NN) ? deg[i] : 0;
    sh[threadIdx.x] = x;
    __syncthreads();
    for (int off = 1; off < 256; off <<= 1) {
        int t = (threadIdx.x >= off) ? sh[threadIdx.x - off] : 0;
        __syncthreads();
        sh[threadIdx.x] += t;
        __syncthreads();
    }
    int incl = sh[threadIdx.x];
    if (i < NN) start[i] = incl - x;
    if (threadIdx.x == 255) bsum[blockIdx.x] = incl;
}

__global__ void scan2_kernel(float* ws) {
    if (threadIdx.x == 0) {
        int* bsum = (int*)(ws + F_BSUM);
        int run = 0;
        for (int b = 0; b < NBLK_N; b++) { int t = bsum[b]; bsum[b] = run; run += t; }
    }
}

__global__ void scan3_kernel(float* ws) {
    int* start  = (int*)(ws + F_START);
    int* cursor = (int*)(ws + F_CURSOR);
    int* bsum   = (int*)(ws + F_BSUM);
    int i = blockIdx.x * 256 + threadIdx.x;
    if (i < NN) {
        int s = start[i] + bsum[i >> 8];
        start[i] = s;
        cursor[i] = s;
        if (i == 0) start[NN] = NE;
    }
}

__global__ void fill_kernel(const int* __restrict__ nto, float* ws) {
    int e = blockIdx.x * 256 + threadIdx.x;
    if (e < NE) {
        int v = nto[e];
        int pos = atomicAdd(&((int*)(ws + F_CURSOR))[v], 1);
        ((int*)(ws + F_ELIST))[pos] = e;    // CSR pos -> edge
    }
}

// reorder nfrom/ec into CSR(nto) order: edge kernel loads become sequential.
__global__ void pack_kernel(const int* __restrict__ nfrom, const void* __restrict__ ec,
                            const void* __restrict__ g1raw, float* ws) {
    int pos = blockIdx.x * 256 + threadIdx.x;
    if (pos < NE) {
        int e = ((const int*)(ws + F_ELIST))[pos];
        ((int*)(ws + F_USRC))[pos] = nfrom[e];
        ws[F_ECP + pos] = ldf(ec, e, is_bf16(g1raw));
    }
}

// graph CSR: nodes bucketed by graph (no fp32 atomics in readout path).
__global__ void ghist_kernel(const int* __restrict__ gidx, float* ws) {
    int i = blockIdx.x * 256 + threadIdx.x;
    if (i < NN) atomicAdd(&((int*)(ws + F_GDEG))[gidx[i]], 1);
}

__global__ void gscan_kernel(float* ws) {
    __shared__ int sh[1024];
    int* deg   = (int*)(ws + F_GDEG);
    int* start = (int*)(ws + F_GSTART);
    int* cur   = (int*)(ws + F_GCUR);
    int t = threadIdx.x;
    int x = (t < NG) ? deg[t] : 0;
    sh[t] = x;
    __syncthreads();
    for (int off = 1; off < 1024; off <<= 1) {
        int v = (t >= off) ? sh[t - off] : 0;
        __syncthreads();
        sh[t] += v;
        __syncthreads();
    }
    if (t < NG) { start[t] = sh[t] - x; cur[t] = sh[t] - x; }
    if (t == 0) start[NG] = NN;
}

__global__ void gfill_kernel(const int* __restrict__ gidx, float* ws) {
    int i = blockIdx.x * 256 + threadIdx.x;
    if (i < NN) {
        int pos = atomicAdd(&((int*)(ws + F_GCUR))[gidx[i]], 1);
        ((int*)(ws + F_GLIST))[pos] = i;
    }
}

// ---------------- node kernel: gather msgs + update state + z + LN1 stats ----------------
// One wave per 16 nodes. Lane layout: col = node, quad = 8-dim block.
// After gather+update, lane's 8 state dims ARE the MFMA A-frag (k=quad*8+j).
// z = state@W1[:32] + b1 (8 MFMA, K=32 exact). Per-node scalars
// {sum(z), sum(z^2), dot(z, w1last)} make per-edge LN1 stats closed-form.
__launch_bounds__(256)
__global__ void node_kernel(float* __restrict__ ws, int do_gather, int do_z)
{
    __shared__ unsigned short zl[4][16 * 136];
    const int wv = threadIdx.x >> 6, lane = threadIdx.x & 63;
    const int col = lane & 15, quad = lane >> 4;
    const long vbase = ((long)blockIdx.x * 4 + wv) * 16;
    if (vbase >= NN) return;
    const int v = (int)vbase + col;

    float st[8];
    float* sp = ws + OFF_STATE + (long)v * SS + quad * 8;
    {
        f32x4 s0 = *(const f32x4*)sp;
        f32x4 s1 = *(const f32x4*)(sp + 4);
        st[0] = s0[0]; st[1] = s0[1]; st[2] = s0[2]; st[3] = s0[3];
        st[4] = s1[0]; st[5] = s1[1]; st[6] = s1[2]; st[7] = s1[3];
    }
    if (do_gather) {
        const int* start = (const int*)(ws + F_START);
        int p0 = start[v], p1 = start[v + 1];
        const u32x4* mb = (const u32x4*)(ws + F_MSG);
        for (int p = p0; p < p1; ++p) {
            u32x4 m = mb[(long)p * 4 + quad];   // lanes {col,col+16,..}: contiguous 64B
            st[0] += lo_bf(m[0]); st[1] += hi_bf(m[0]);
            st[2] += lo_bf(m[1]); st[3] += hi_bf(m[1]);
            st[4] += lo_bf(m[2]); st[5] += hi_bf(m[2]);
            st[6] += lo_bf(m[3]); st[7] += hi_bf(m[3]);
        }
        f32x4 s0, s1;
        s0[0] = st[0]; s0[1] = st[1]; s0[2] = st[2]; s0[3] = st[3];
        s1[0] = st[4]; s1[1] = st[5]; s1[2] = st[6]; s1[3] = st[7];
        *(f32x4*)sp = s0;
        *(f32x4*)(sp + 4) = s1;
    }
    if (!do_z) return;

    // A-frag: this lane's own 8 dims, bf16-packed.
    u32x4 au;
    au[0] = cvt2bf(st[0], st[1]);
    au[1] = cvt2bf(st[2], st[3]);
    au[2] = cvt2bf(st[4], st[5]);
    au[3] = cvt2bf(st[6], st[7]);
    s16x8 af = as_s16x8(au);

    const u32x4* W1B = (const u32x4*)(ws + OFF_W1B);
    const float* B1 = ws + OFF_B1;
    f32x4 acc[8];
#pragma unroll
    for (int t = 0; t < 8; t++) {
        float bb = B1[t * 16 + col];
        acc[t][0] = bb; acc[t][1] = bb; acc[t][2] = bb; acc[t][3] = bb;
        acc[t] = __builtin_amdgcn_mfma_f32_16x16x32_bf16(af, as_s16x8(W1B[t * 64 + lane]), acc[t], 0, 0, 0);
    }

    // per-node stats: sum, sumsq, dot(z, w1last). rows m = quad*4+r.
    float s[4] = {0.f, 0.f, 0.f, 0.f}, q[4] = {0.f, 0.f, 0.f, 0.f}, d[4] = {0.f, 0.f, 0.f, 0.f};
    const float* W1L = ws + OFF_W1L;
#pragma unroll
    for (int t = 0; t < 8; t++) {
        float wl = W1L[t * 16 + col];
#pragma unroll
        for (int r = 0; r < 4; r++) {
            float z = acc[t][r];
            s[r] += z; q[r] = fmaf(z, z, q[r]); d[r] = fmaf(z, wl, d[r]);
        }
    }
#pragma unroll
    for (int r = 0; r < 4; r++) {
        float sr = row_reduce16(s[r]);
        float qr = row_reduce16(q[r]);
        float dr = row_reduce16(d[r]);
        if (col == 0) {
            f32x4 o; o[0] = sr; o[1] = qr; o[2] = dr; o[3] = 0.f;
            *(f32x4*)(ws + F_ZST + (vbase + quad * 4 + r) * 4) = o;
        }
    }

    // z -> LDS transpose (scalar b16, cheap at N/16 waves) -> coalesced global.
    unsigned short* zw_ = zl[wv];
#pragma unroll
    for (int t = 0; t < 8; t++) {
        unsigned int p01 = cvt2bf(acc[t][0], acc[t][1]);
        unsigned int p23 = cvt2bf(acc[t][2], acc[t][3]);
        unsigned short* b = zw_ + quad * (4 * 136) + t * 16 + col;
        b[0]       = (unsigned short)p01;
        b[136]     = (unsigned short)(p01 >> 16);
        b[2 * 136] = (unsigned short)p23;
        b[3 * 136] = (unsigned short)(p23 >> 16);
    }
    unsigned int* zg = (unsigned int*)(ws + F_Z) + vbase * 64;
#pragma unroll
    for (int it = 0; it < 4; it++) {
        int byte = it * 1024 + lane * 16;
        int node = byte >> 8;
        int ko   = (byte & 255) >> 1;
        u32x4 val = *(const u32x4*)(zw_ + node * 136 + ko);
        *(u32x4*)(zg + it * 256 + lane * 4) = val;
    }
}

// ---------------- edge kernel: per-edge LN1(closed form) + layer2 MFMA ----------------
// One wave per 16 edges in destination-CSR order. NO LDS, NO barriers.
// h(e) = lrelu(LN(z[u] + ec*w1last)) built in-register directly in the
// B-frag layout (z stored row-major [node][feat], lane reads feats quad*8+j).
// Layer2 operand-swapped: D[msgdim][edge] = mfma(A=W2^T frag, B=h frag).
__launch_bounds__(256)
__global__ void edge2_kernel(float* __restrict__ ws)
{
    const int lane = threadIdx.x & 63, wv = threadIdx.x >> 6;
    const int col = lane & 15, quad = lane >> 4;
    const long e_base = ((long)blockIdx.x * 4 + wv) * 16;
    const int epos = (int)e_base + col;

    const int u    = ((const int*)(ws + F_USRC))[epos];
    const float ecv = ws[F_ECP + epos];

    // closed-form LN1 stats
    f32x4 zst = *(const f32x4*)(ws + F_ZST + (long)u * 4);   // {sumz, sqz, dzw, 0}
    const float sw1 = ws[OFF_WSC], sqw1 = ws[OFF_WSC + 1];
    float sumh = fmaf(ecv, sw1, zst[0]);
    float sqh  = fmaf(ecv, fmaf(ecv, sqw1, 2.f * zst[2]), zst[1]);
    float mean = sumh * (1.f / HH);
    float var  = fmaxf(sqh * (1.f / HH) - mean * mean, 0.f);
    float inv  = rsqrtf(var + EPS);
    const float alpha = inv, beta = -mean * inv;

    // acc init = b2[msgdim]; msgdim = t2*16 + quad*4 + r
    f32x4 acc2[2];
#pragma unroll
    for (int t2 = 0; t2 < 2; t2++)
        acc2[t2] = *(const f32x4*)(ws + OFF_B2 + t2 * 16 + quad * 4);

    const unsigned int* zrow = (const unsigned int*)(ws + F_Z) + (long)u * 64;
    const u32x4* W2F = (const u32x4*)(ws + OFF_W2F);
#pragma unroll
    for (int ks = 0; ks < 4; ks++) {
        u32x4 zwv = *(const u32x4*)(zrow + ks * 16 + quad * 4);
        const int n0 = ks * 32 + quad * 8;
        f32x4 wlA = *(const f32x4*)(ws + OFF_W1L + n0);
        f32x4 wlB = *(const f32x4*)(ws + OFF_W1L + n0 + 4);
        f32x4 gA  = *(const f32x4*)(ws + OFF_G1  + n0);
        f32x4 gB  = *(const f32x4*)(ws + OFF_G1  + n0 + 4);
        f32x4 bA  = *(const f32x4*)(ws + OFF_BE1 + n0);
        f32x4 bB  = *(const f32x4*)(ws + OFF_BE1 + n0 + 4);
        float wl[8] = {wlA[0], wlA[1], wlA[2], wlA[3], wlB[0], wlB[1], wlB[2], wlB[3]};
        float gg[8] = {gA[0], gA[1], gA[2], gA[3], gB[0], gB[1], gB[2], gB[3]};
        float bb[8] = {bA[0], bA[1], bA[2], bA[3], bB[0], bB[1], bB[2], bB[3]};
        u32x4 hu;
#pragma unroll
        for (int w = 0; w < 4; w++) {
            float z0 = lo_bf(zwv[w]), z1 = hi_bf(zwv[w]);
            float h0 = fmaf(ecv, wl[2 * w],     z0);
            float h1 = fmaf(ecv, wl[2 * w + 1], z1);
            h0 = fmaf(h0, alpha, beta);          h1 = fmaf(h1, alpha, beta);
            h0 = fmaf(h0, gg[2 * w], bb[2 * w]); h1 = fmaf(h1, gg[2 * w + 1], bb[2 * w + 1]);
            h0 = fmaxf(h0, NEG * h0);            h1 = fmaxf(h1, NEG * h1);
            hu[w] = cvt2bf(h0, h1);
        }
        s16x8 hf = as_s16x8(hu);
        acc2[0] = __builtin_amdgcn_mfma_f32_16x16x32_bf16(as_s16x8(W2F[(ks * 2 + 0) * 64 + lane]), hf, acc2[0], 0, 0, 0);
        acc2[1] = __builtin_amdgcn_mfma_f32_16x16x32_bf16(as_s16x8(W2F[(ks * 2 + 1) * 64 + lane]), hf, acc2[1], 0, 0, 0);
    }

    // LN2: lane holds 8 of 32 msg dims for its edge (col); reduce across quads.
    float s2 = 0.f, q2 = 0.f;
#pragma unroll
    for (int t2 = 0; t2 < 2; t2++)
#pragma unroll
        for (int r = 0; r < 4; r++) { float vv = acc2[t2][r]; s2 += vv; q2 = fmaf(vv, vv, q2); }
    s2 += __shfl_xor(s2, 16); q2 += __shfl_xor(q2, 16);
    s2 += __shfl_xor(s2, 32); q2 += __shfl_xor(q2, 32);
    float mean2 = s2 * (1.f / SS);
    float var2  = fmaxf(q2 * (1.f / SS) - mean2 * mean2, 0.f);
    float inv2  = rsqrtf(var2 + EPS);
    const float a2 = inv2, b2c = -mean2 * inv2;

    // store: CSR-ordered -> wave writes 16 edges x 64B = 1KB contiguous.
    unsigned int* dst = (unsigned int*)(ws + F_MSG) + (long)epos * 16;
#pragma unroll
    for (int t2 = 0; t2 < 2; t2++) {
        f32x4 g = *(const f32x4*)(ws + OFF_G2  + t2 * 16 + quad * 4);
        f32x4 b = *(const f32x4*)(ws + OFF_BE2 + t2 * 16 + quad * 4);
        float m0 = fmaf(fmaf(acc2[t2][0], a2, b2c), g[0], b[0]);
        float m1 = fmaf(fmaf(acc2[t2][1], a2, b2c), g[1], b[1]);
        float m2 = fmaf(fmaf(acc2[t2][2], a2, b2c), g[2], b[2]);
        float m3 = fmaf(fmaf(acc2[t2][3], a2, b2c), g[3], b[3]);
        m0 = fmaxf(m0, NEG * m0); m1 = fmaxf(m1, NEG * m1);
        m2 = fmaxf(m2, NEG * m2); m3 = fmaxf(m3, NEG * m3);
        uint2 o; o.x = cvt2bf(m0, m1); o.y = cvt2bf(m2, m3);
        *(uint2*)(dst + t2 * 8 + quad * 2) = o;   // dims {4q..4q+3} and {16+4q..}
    }
}

// graph segment-sum via CSR: 32 lanes per graph, no atomics.
__launch_bounds__(256)
__global__ void graph_gather_kernel(float* __restrict__ ws)
{
    int t = blockIdx.x * 256 + threadIdx.x;
    int g = t >> 5;
    if (g >= NG) return;
    int j = t & 31;
    const int* start = (const int*)(ws + F_GSTART);
    const int* list  = (const int*)(ws + F_GLIST);
    int s0 = start[g], s1 = start[g + 1];
    float acc = 0.f;
    for (int p = s0; p < s1; ++p)
        acc += ws[OFF_STATE + (long)list[p] * SS + j];
    ws[OFF_GS + (long)g * SS + j] = acc;
}

// ---------------- fallback (atomic) path ----------------
__launch_bounds__(256)
__global__ void edge_atomic_kernel(const int* __restrict__ nfrom, const int* __restrict__ nto,
                                   const void* __restrict__ ec, const void* __restrict__ g1raw,
                                   const float* __restrict__ cws, float* delta)
{
    int e = blockIdx.x * 256 + threadIdx.x;
    if (e >= NE) return;
    const float* state = cws + OFF_STATE;
    const float* W1T = cws + OFF_W1T;
    const float* B1  = cws + OFF_B1;
    const float* G1  = cws + OFF_G1;
    const float* BE1 = cws + OFF_BE1;
    const float* W2  = cws + OFF_W2;
    const float* B2  = cws + OFF_B2;
    const float* G2  = cws + OFF_G2;
    const float* BE2 = cws + OFF_BE2;
    int u = nfrom[e];
    float inp[33];
    const float4* srow = (const float4*)(state + (long)u * SS);
#pragma unroll
    for (int i = 0; i < 8; i++) {
        float4 v = srow[i];
        inp[i * 4 + 0] = v.x; inp[i * 4 + 1] = v.y;
        inp[i * 4 + 2] = v.z; inp[i * 4 + 3] = v.w;
    }
    inp[32] = ldf(ec, e, is_bf16(g1raw));
    float sum = 0.f, sq = 0.f;
    for (int k = 0; k < HH; k++) {
        const float* wr = W1T + k * 33;
        float a = B1[k];
#pragma unroll
        for (int i = 0; i < 33; i++) a = fmaf(inp[i], wr[i], a);
        sum += a; sq = fmaf(a, a, sq);
    }
    float mean = sum * (1.f / HH);
    float var  = sq * (1.f / HH) - mean * mean;
    float inv  = rsqrtf(var + EPS);
    float msg[SS];
#pragma unroll
    for (int j = 0; j < SS; j++) msg[j] = B2[j];
    for (int k = 0; k < HH; k++) {
        const float* wr = W1T + k * 33;
        float a = B1[k];
#pragma unroll
        for (int i = 0; i < 33; i++) a = fmaf(inp[i], wr[i], a);
        float hk = fmaf((a - mean) * inv, G1[k], BE1[k]);
        hk = hk >= 0.f ? hk : NEG * hk;
        const float* w2r = W2 + k * SS;
#pragma unroll
        for (int j = 0; j < SS; j++) msg[j] = fmaf(hk, w2r[j], msg[j]);
    }
    float s2 = 0.f, q2 = 0.f;
#pragma unroll
    for (int j = 0; j < SS; j++) { s2 += msg[j]; q2 = fmaf(msg[j], msg[j], q2); }
    float m2 = s2 * (1.f / SS);
    float v2 = q2 * (1.f / SS) - m2 * m2;
    float i2 = rsqrtf(v2 + EPS);
    int v = nto[e];
    float* drow = delta + (long)v * SS;
#pragma unroll
    for (int j = 0; j < SS; j++) {
        float mj = fmaf((msg[j] - m2) * i2, G2[j], BE2[j]);
        mj = mj >= 0.f ? mj : NEG * mj;
        atomicAdd(drow + j, mj);
    }
}

__global__ void update_kernel(float* ws)
{
    long idx = (long)blockIdx.x * blockDim.x + threadIdx.x;
    if (idx < (long)NN * SS) {
        ws[OFF_STATE + idx] += ws[OFF_DELTA + idx];
        ws[OFF_DELTA + idx] = 0.f;
    }
}

__global__ void graph_kernel(const int* __restrict__ gidx, float* ws)
{
    long idx = (long)blockIdx.x * blockDim.x + threadIdx.x;
    if (idx < (long)NN * SS) {
        int i = (int)(idx >> 5);
        int j = (int)(idx & 31);
        atomicAdd(&ws[OFF_GS + (long)gidx[i] * SS + j], ws[OFF_STATE + idx]);
    }
}

// ---------------- readout ----------------
__global__ void readout_kernel(const float* __restrict__ ws, const void* __restrict__ g1raw,
                               void* __restrict__ out)
{
    int g = blockIdx.x;
    int j = threadIdx.x;
    __shared__ float row[SS];
    __shared__ float buf[HH];
    __shared__ float p0[HH];
    __shared__ float p1[HH];

    const float* gs  = ws + OFF_GS;
    const float* Wo1 = ws + OFF_WO1;
    if (j < SS) row[j] = gs[(long)g * SS + j];
    __syncthreads();

    float a = ws[OFF_BO1 + j];
#pragma unroll
    for (int i = 0; i < SS; i++) a = fmaf(row[i], Wo1[i * HH + j], a);
    buf[j] = a;
    __syncthreads();

    float sum = 0.f, sq = 0.f;
    for (int i = 0; i < HH; i++) { float x = buf[i]; sum += x; sq = fmaf(x, x, sq); }
    float mean = sum * (1.f / HH);
    float var  = sq * (1.f / HH) - mean * mean;
    float inv  = rsqrtf(var + EPS);
    float h = fmaf((a - mean) * inv, ws[OFF_GO + j], ws[OFF_BEO + j]);
    h = h >= 0.f ? h : NEG * h;

    p0[j] = h * ws[OFF_WO2 + j * 2 + 0];
    p1[j] = h * ws[OFF_WO2 + j * 2 + 1];
    __syncthreads();

    if (j == 0) {
        float e0 = ws[OFF_BO2 + 0], e1 = ws[OFF_BO2 + 1];
        for (int i = 0; i < HH; i++) { e0 += p0[i]; e1 += p1[i]; }
        float sp = (e1 > 20.f) ? e1 : log1pf(expf(e1));
        if (is_bf16(g1raw)) {
            __hip_bfloat16* o = (__hip_bfloat16*)out;
            o[g * 2 + 0] = __float2bfloat16(e0);
            o[g * 2 + 1] = __float2bfloat16(sp);
        } else {
            float* o = (float*)out;
            o[g * 2 + 0] = e0;
            o[g * 2 + 1] = sp;
        }
    }
}

extern "C" void kernel_launch(void* const* d_in, const int* in_sizes, int n_in,
                              void* d_out, int out_size, void* d_ws, size_t ws_size,
                              hipStream_t stream)
{
    const int* nfrom = (const int*)d_in[0];
    const int* nto   = (const int*)d_in[1];
    const void* ec   = d_in[2];
    const int* gidx  = (const int*)d_in[3];
    const void* W1  = d_in[6];
    const void* b1  = d_in[7];
    const void* g1  = d_in[8];
    const void* be1 = d_in[9];
    const void* W2  = d_in[10];
    const void* b2  = d_in[11];
    const void* g2  = d_in[12];
    const void* be2 = d_in[13];
    const void* Wo1 = d_in[14];
    const void* bo1 = d_in[15];
    const void* go  = d_in[16];
    const void* beo = d_in[17];
    const void* Wo2 = d_in[18];
    const void* bo2 = d_in[19];

    float* ws = (float*)d_ws;
    if (ws_size < (size_t)WS_FALLBACK * sizeof(float)) return;
    const bool gather = ws_size >= (size_t)WS_TOTAL * sizeof(float);

    const int nsBlocks = (int)(((long)NN * SS + 255) / 256);   // 12500
    const int eBlocks  = (NE + 255) / 256;                     // 6250
    const int efBlocks = NE / 64;                              // 25000 (4 waves x 16 edges)
    const int ndBlocks = (NN / 16 + 3) / 4;                    // 1563  (4 waves x 16 nodes)
    const int nBlocks1 = (NN + 255) / 256;                     // 391

    prep_kernel<<<nsBlocks, 256, 0, stream>>>(W1, b1, g1, be1, W2, b2, g2, be2,
                                              Wo1, bo1, go, beo, Wo2, bo2, ws);
    if (gather) {
        hist_kernel <<<eBlocks, 256, 0, stream>>>(nto, ws);
        scan1_kernel<<<NBLK_N, 256, 0, stream>>>(ws);
        scan2_kernel<<<1, 64, 0, stream>>>(ws);
        scan3_kernel<<<NBLK_N, 256, 0, stream>>>(ws);
        fill_kernel <<<eBlocks, 256, 0, stream>>>(nto, ws);
        pack_kernel <<<eBlocks, 256, 0, stream>>>(nfrom, ec, g1, ws);
        ghist_kernel<<<nBlocks1, 256, 0, stream>>>(gidx, ws);
        gscan_kernel<<<1, 1024, 0, stream>>>(ws);
        gfill_kernel<<<nBlocks1, 256, 0, stream>>>(gidx, ws);
        // round 0: state = 0 -> z0 + stats (no gather)
        node_kernel<<<ndBlocks, 256, 0, stream>>>(ws, 0, 1);
        for (int r = 0; r < ROUNDS; r++) {
            edge2_kernel<<<efBlocks, 256, 0, stream>>>(ws);
            node_kernel <<<ndBlocks, 256, 0, stream>>>(ws, 1, (r < ROUNDS - 1) ? 1 : 0);
        }
        graph_gather_kernel<<<(NG * 32 + 255) / 256, 256, 0, stream>>>(ws);
    } else {
        for (int r = 0; r < ROUNDS; r++) {
            edge_atomic_kernel<<<eBlocks, 256, 0, stream>>>(nfrom, nto, ec, g1, ws, ws + OFF_DELTA);
            update_kernel<<<nsBlocks, 256, 0, stream>>>(ws);
        }
        graph_kernel<<<nsBlocks, 256, 0, stream>>>(gidx, ws);
    }
    readout_kernel<<<NG, HH, 0, stream>>>(ws, g1, (void*)d_out);
}

// Round 2
// 1422.804 us; speedup vs baseline: 1.0375x; 1.0375x over previous
//
#include <hip/hip_runtime.h>
#include <hip/hip_bf16.h>

#define NN 100000
#define NE 1600000
#define NG 1000
#define SS 32
#define HH 128
#define ROUNDS 5

constexpr float NEG = 0.01f;
constexpr float EPS = 1e-5f;

constexpr long al4(long x)  { return (x + 3) & ~3L; }
constexpr long al16(long x) { return (x + 15) & ~15L; }

// ---- workspace layout (float-slot offsets) ----
constexpr long OFF_STATE = 0;                          // N*S fp32
constexpr long OFF_GS    = OFF_STATE + (long)NN * SS;  // G*S
constexpr long OFF_W1T   = OFF_GS + (long)NG * SS;     // 128*33 (transposed, fallback)
constexpr long OFF_B1    = OFF_W1T + HH * 33;
constexpr long OFF_G1    = OFF_B1 + HH;
constexpr long OFF_BE1   = OFF_G1 + HH;
constexpr long OFF_W2    = OFF_BE1 + HH;               // 128*32 row-major (fallback)
constexpr long OFF_B2    = OFF_W2 + HH * SS;
constexpr long OFF_G2    = OFF_B2 + SS;
constexpr long OFF_BE2   = OFF_G2 + SS;
constexpr long OFF_WO1   = OFF_BE2 + SS;               // 32*128 row-major
constexpr long OFF_BO1   = OFF_WO1 + SS * HH;
constexpr long OFF_GO    = OFF_BO1 + HH;
constexpr long OFF_BEO   = OFF_GO + HH;
constexpr long OFF_WO2   = OFF_BEO + HH;               // 128*2
constexpr long OFF_BO2   = OFF_WO2 + HH * 2;
constexpr long OFF_W1L   = al4(OFF_BO2 + 2);           // 128 f32: W1 row 32 (ec weights)
constexpr long OFF_WSC   = OFF_W1L + HH;               // 2 f32: sum(w1l), sum(w1l^2)
// MFMA fragment tables (bf16 pairs, one u32 word per 2 k-elems):
// W1B: [t(8)][lane(64)][q(4)] (node kernel). W2F: [ks(4)][t2(2)][lane(64)][q(4)].
constexpr long OFF_W1B   = al4(OFF_WSC + 2);           // 2048 u32 words
constexpr long OFF_W2F   = OFF_W1B + 2048;             // 2048 u32 words
constexpr long W_END     = OFF_W2F + 2048;
// gather-path regions. OFF_DELTA (fallback) ALIASES F_Z — safe: paths are
// mutually exclusive and prep zeros DELTA; z is fully rewritten before reads.
constexpr long OFF_DELTA = al4(W_END);                 // N*S fp32 (fallback only)
// z-row: 68 u32 per node = 128 bf16 z (64 u32) + {sumz,sqz,dzw,pad} f32 (4)
constexpr long F_Z      = al4(W_END);
constexpr long F_DEG    = al4(F_Z + (long)NN * 68);    // N int (dest degree)
constexpr long F_START  = F_DEG + NN;                  // N+4 int (dest CSR start)
constexpr long F_CURSOR = F_START + NN + 4;            // N int
constexpr long F_SDEG   = F_CURSOR + NN;               // N int (src degree)
constexpr long F_SSTART = F_SDEG + NN;                 // N+4 int
constexpr long F_SCUR   = F_SSTART + NN + 4;           // N int
constexpr long F_BSUM   = F_SCUR + NN;                 // 512 int (scan temp, reused)
constexpr long F_GDEG   = F_BSUM + 512;                // G int
constexpr long F_GSTART = F_GDEG + NG;                 // G+4 int
constexpr long F_GCUR   = F_GSTART + NG + 4;           // G int
constexpr long F_GLIST  = F_GCUR + NG;                 // N int (nodes sorted by graph)
constexpr long F_EPK    = al16(F_GLIST + NN);          // E x {u, ec_bits, dest_slot, 0}
constexpr long F_MSG    = al16(F_EPK + (long)NE * 4);  // E*S bf16 = E*16 u32 slots
constexpr long F_DSLBYE = F_MSG;                       // E int, ALIASES MSG (build-time only)
constexpr long WS_TOTAL = F_MSG + (long)NE * 16;
constexpr long WS_FALLBACK = OFF_DELTA + (long)NN * SS;
constexpr int  NBLK_N  = (NN + 255) / 256;             // 391

typedef float f32x4 __attribute__((ext_vector_type(4)));
typedef unsigned int u32x4 __attribute__((ext_vector_type(4)));
typedef short s16x8 __attribute__((ext_vector_type(8)));

__device__ __forceinline__ s16x8 as_s16x8(u32x4 u) {
    union { u32x4 a; s16x8 b; } c; c.a = u; return c.b;
}
__device__ __forceinline__ float bf2f(unsigned short u) {
    union { unsigned int i; float f; } v;
    v.i = ((unsigned int)u) << 16;
    return v.f;
}
__device__ __forceinline__ float lo_bf(unsigned int p) {
    union { unsigned int i; float f; } v; v.i = p << 16; return v.f;
}
__device__ __forceinline__ float hi_bf(unsigned int p) {
    union { unsigned int i; float f; } v; v.i = p & 0xFFFF0000u; return v.f;
}
__device__ __forceinline__ unsigned short f2bf(float f) {
    union { float f; unsigned int u; } x; x.f = f;
    return (unsigned short)((x.u + 0x7FFFu + ((x.u >> 16) & 1u)) >> 16);
}
__device__ __forceinline__ unsigned int pack_bf2(float a, float b) {
    return (unsigned int)f2bf(a) | ((unsigned int)f2bf(b) << 16);
}
#if defined(__has_builtin)
#if __has_builtin(__builtin_amdgcn_cvt_pk_bf16_f32)
#define HAVE_CVT_PK_BF16 1
#endif
#endif
__device__ __forceinline__ unsigned int cvt2bf(float a, float b) {
#ifdef HAVE_CVT_PK_BF16
    auto r = __builtin_amdgcn_cvt_pk_bf16_f32(a, b);   // lo=a, hi=b
    unsigned int u; __builtin_memcpy(&u, &r, 4); return u;
#else
    return pack_bf2(a, b);
#endif
}
// DPP row-rotate add reduction over a 16-lane row (pure VALU, no LDS pipe).
template <int CTRL>
__device__ __forceinline__ float ror_add(float x) {
    int v = __builtin_amdgcn_update_dpp(0, __float_as_int(x), CTRL, 0xF, 0xF, true);
    return x + __int_as_float(v);
}
__device__ __forceinline__ float row_reduce16(float x) {
    x = ror_add<0x121>(x);
    x = ror_add<0x122>(x);
    x = ror_add<0x124>(x);
    x = ror_add<0x128>(x);
    return x;
}
// Dtype self-detection: g1 is all-1.0. fp32 -> low16 of first u32 == 0.
__device__ __forceinline__ int is_bf16(const void* g1raw) {
    return (((const unsigned int*)g1raw)[0] & 0xFFFFu) != 0u;
}
__device__ __forceinline__ float ldf(const void* p, long idx, int bf) {
    return bf ? bf2f(((const unsigned short*)p)[idx]) : ((const float*)p)[idx];
}

// Zero state/gs/deg/sdeg/gdeg/delta-alias; fp32 weight tables; MFMA frag tables.
__global__ void prep_kernel(
    const void* __restrict__ W1,  const void* __restrict__ b1,
    const void* __restrict__ g1,  const void* __restrict__ be1,
    const void* __restrict__ W2,  const void* __restrict__ b2,
    const void* __restrict__ g2,  const void* __restrict__ be2,
    const void* __restrict__ Wo1, const void* __restrict__ bo1,
    const void* __restrict__ go,  const void* __restrict__ beo,
    const void* __restrict__ Wo2, const void* __restrict__ bo2,
    float* __restrict__ ws)
{
    const int bf = is_bf16(g1);
    long idx = (long)blockIdx.x * blockDim.x + threadIdx.x;
    if (idx < (long)NN * SS) { ws[OFF_STATE + idx] = 0.f; ws[OFF_DELTA + idx] = 0.f; }
    if (idx < (long)NG * SS) ws[OFF_GS + idx] = 0.f;
    if (idx < NN) { ((int*)(ws + F_DEG))[idx] = 0; ((int*)(ws + F_SDEG))[idx] = 0; }
    if (idx < NG) ((int*)(ws + F_GDEG))[idx] = 0;
    if (idx < 33 * HH) {
        int i = (int)(idx / HH), k = (int)(idx % HH);
        ws[OFF_W1T + (long)k * 33 + i] = ldf(W1, idx, bf);
    }
    if (idx < HH) {
        ws[OFF_B1  + idx] = ldf(b1,  idx, bf);
        ws[OFF_G1  + idx] = ldf(g1,  idx, bf);
        ws[OFF_BE1 + idx] = ldf(be1, idx, bf);
        ws[OFF_BO1 + idx] = ldf(bo1, idx, bf);
        ws[OFF_GO  + idx] = ldf(go,  idx, bf);
        ws[OFF_BEO + idx] = ldf(beo, idx, bf);
        ws[OFF_W1L + idx] = ldf(W1, (long)32 * HH + idx, bf);   // W1 last row (ec)
    }
    if (idx == 0) {
        float sw = 0.f, sq = 0.f;
        for (int i = 0; i < HH; i++) {
            float w = ldf(W1, (long)32 * HH + i, bf);
            sw += w; sq = fmaf(w, w, sq);
        }
        ws[OFF_WSC] = sw; ws[OFF_WSC + 1] = sq;
    }
    if (idx < HH * SS) ws[OFF_W2 + idx] = ldf(W2, idx, bf);
    if (idx < SS) {
        ws[OFF_B2  + idx] = ldf(b2,  idx, bf);
        ws[OFF_G2  + idx] = ldf(g2,  idx, bf);
        ws[OFF_BE2 + idx] = ldf(be2, idx, bf);
    }
    if (idx < SS * HH) ws[OFF_WO1 + idx] = ldf(Wo1, idx, bf);
    if (idx < HH * 2)  ws[OFF_WO2 + idx] = ldf(Wo2, idx, bf);
    if (idx < 2)       ws[OFF_BO2 + idx] = ldf(bo2, idx, bf);
    // W1B: B-frag for z = state*W1[:32]. word w = (t*64+L)*4+q holds
    // k = (L>>4)*8+2q (+1), n = t*16+(L&15).
    if (idx < 2048) {
        int w = (int)idx;
        int qq = w & 3, L = (w >> 2) & 63, t = (int)(w >> 8);
        int k0 = (L >> 4) * 8 + 2 * qq;
        int n  = t * 16 + (L & 15);
        ((unsigned int*)(ws + OFF_W1B))[w] =
            pack_bf2(ldf(W1, (long)k0 * HH + n, bf), ldf(W1, (long)(k0 + 1) * HH + n, bf));
    }
    // W2F: word w = ((ks*2+t2)*64+L)*4+q ; k = ks*32+(L>>4)*8+2q, n = t2*16+(L&15)
    // (operand-swapped use: A-frag [m=n][k] of W2^T)
    if (idx < 2048) {
        int w = (int)idx;
        int qq = w & 3, L = (w >> 2) & 63, t2 = (w >> 8) & 1, ks = (int)(w >> 9);
        int k0 = ks * 32 + (L >> 4) * 8 + 2 * qq;
        int n  = t2 * 16 + (L & 15);
        float v0 = ldf(W2, (long)k0 * SS + n, bf);
        float v1 = ldf(W2, (long)(k0 + 1) * SS + n, bf);
        ((unsigned int*)(ws + OFF_W2F))[w] = pack_bf2(v0, v1);
    }
}

// ---------------- CSR builds (once per launch) ----------------
// dest + src degree histograms in one pass over the edge list.
__global__ void hist2_kernel(const int* __restrict__ nto, const int* __restrict__ nfrom,
                             float* ws) {
    int e = blockIdx.x * 256 + threadIdx.x;
    if (e < NE) {
        atomicAdd(&((int*)(ws + F_DEG))[nto[e]], 1);
        atomicAdd(&((int*)(ws + F_SDEG))[nfrom[e]], 1);
    }
}

// generic N-element scan over (deg -> start); bsum shared scratch.
__global__ void scan1_kernel(float* ws, long degOff, long startOff) {
    __shared__ int sh[256];
    int* deg   = (int*)(ws + degOff);
    int* start = (int*)(ws + startOff);
    int* bsum  = (int*)(ws + F_BSUM);
    int i = blockIdx.x * 256 + threadIdx.x;
    int x = (i < NN) ? deg[i] : 0;
    sh[threadIdx.x] = x;
    __syncthreads();
    for (int off = 1; off < 256; off <<= 1) {
        int t = (threadIdx.x >= off) ? sh[threadIdx.x - off] : 0;
        __syncthreads();
        sh[threadIdx.x] += t;
        __syncthreads();
    }
    int incl = sh[threadIdx.x];
    if (i < NN) start[i] = incl - x;
    if (threadIdx.x == 255) bsum[blockIdx.x] = incl;
}

__global__ void scan2_kernel(float* ws) {
    if (threadIdx.x == 0) {
        int* bsum = (int*)(ws + F_BSUM);
        int run = 0;
        for (int b = 0; b < NBLK_N; b++) { int t = bsum[b]; bsum[b] = run; run += t; }
    }
}

__global__ void scan3_kernel(float* ws, long startOff, long curOff) {
    int* start  = (int*)(ws + startOff);
    int* cursor = (int*)(ws + curOff);
    int* bsum   = (int*)(ws + F_BSUM);
    int i = blockIdx.x * 256 + threadIdx.x;
    if (i < NN) {
        int s = start[i] + bsum[i >> 8];
        start[i] = s;
        cursor[i] = s;
        if (i == 0) start[NN] = NE;
    }
}

// dest slot per edge (sequential write, consumed by fill2).
__global__ void fill1_kernel(const int* __restrict__ nto, float* ws) {
    int e = blockIdx.x * 256 + threadIdx.x;
    if (e < NE) {
        int v = nto[e];
        int pos = atomicAdd(&((int*)(ws + F_CURSOR))[v], 1);
        ((int*)(ws + F_DSLBYE))[e] = pos;
    }
}

// pack {u, ec, dest_slot} into source-CSR order: ONE scattered 16B write/edge.
__global__ void fill2_kernel(const int* __restrict__ nfrom, const void* __restrict__ ec,
                             const void* __restrict__ g1raw, float* ws) {
    int e = blockIdx.x * 256 + threadIdx.x;
    if (e < NE) {
        int u = nfrom[e];
        float ecv = ldf(ec, e, is_bf16(g1raw));
        int dpos = ((const int*)(ws + F_DSLBYE))[e];
        int spos = atomicAdd(&((int*)(ws + F_SCUR))[u], 1);
        union { float f; unsigned int i; } c; c.f = ecv;
        u32x4 o; o[0] = (unsigned int)u; o[1] = c.i; o[2] = (unsigned int)dpos; o[3] = 0u;
        *(u32x4*)((unsigned int*)(ws + F_EPK) + (long)spos * 4) = o;
    }
}

// graph CSR: nodes bucketed by graph (no fp32 atomics in readout path).
__global__ void ghist_kernel(const int* __restrict__ gidx, float* ws) {
    int i = blockIdx.x * 256 + threadIdx.x;
    if (i < NN) atomicAdd(&((int*)(ws + F_GDEG))[gidx[i]], 1);
}

__global__ void gscan_kernel(float* ws) {
    __shared__ int sh[1024];
    int* deg   = (int*)(ws + F_GDEG);
    int* start = (int*)(ws + F_GSTART);
    int* cur   = (int*)(ws + F_GCUR);
    int t = threadIdx.x;
    int x = (t < NG) ? deg[t] : 0;
    sh[t] = x;
    __syncthreads();
    for (int off = 1; off < 1024; off <<= 1) {
        int v = (t >= off) ? sh[t - off] : 0;
        __syncthreads();
        sh[t] += v;
        __syncthreads();
    }
    if (t < NG) { start[t] = sh[t] - x; cur[t] = sh[t] - x; }
    if (t == 0) start[NG] = NN;
}

__global__ void gfill_kernel(const int* __restrict__ gidx, float* ws) {
    int i = blockIdx.x * 256 + threadIdx.x;
    if (i < NN) {
        int pos = atomicAdd(&((int*)(ws + F_GCUR))[gidx[i]], 1);
        ((int*)(ws + F_GLIST))[pos] = i;
    }
}

// ---------------- node kernel: gather msgs + update state + z + LN1 stats ----------------
// One wave per 16 nodes. Lane layout: col = node, quad = 8-dim block.
// z = state@W1[:32] + b1 (8 MFMA). Per-node scalars {sum(z), sum(z^2),
// dot(z,w1last)} stored IN the z-row (stride 68 u32) for one-fetch locality.
__launch_bounds__(256)
__global__ void node_kernel(float* __restrict__ ws, int do_gather, int do_z)
{
    __shared__ unsigned short zl[4][16 * 136];
    const int wv = threadIdx.x >> 6, lane = threadIdx.x & 63;
    const int col = lane & 15, quad = lane >> 4;
    const long vbase = ((long)blockIdx.x * 4 + wv) * 16;
    if (vbase >= NN) return;
    const int v = (int)vbase + col;

    float st[8];
    float* sp = ws + OFF_STATE + (long)v * SS + quad * 8;
    {
        f32x4 s0 = *(const f32x4*)sp;
        f32x4 s1 = *(const f32x4*)(sp + 4);
        st[0] = s0[0]; st[1] = s0[1]; st[2] = s0[2]; st[3] = s0[3];
        st[4] = s1[0]; st[5] = s1[1]; st[6] = s1[2]; st[7] = s1[3];
    }
    if (do_gather) {
        const int* start = (const int*)(ws + F_START);
        int p0 = start[v], p1 = start[v + 1];
        const u32x4* mb = (const u32x4*)(ws + F_MSG);
        for (int p = p0; p < p1; ++p) {
            u32x4 m = mb[(long)p * 4 + quad];   // dest-contiguous 64B rows
            st[0] += lo_bf(m[0]); st[1] += hi_bf(m[0]);
            st[2] += lo_bf(m[1]); st[3] += hi_bf(m[1]);
            st[4] += lo_bf(m[2]); st[5] += hi_bf(m[2]);
            st[6] += lo_bf(m[3]); st[7] += hi_bf(m[3]);
        }
        f32x4 s0, s1;
        s0[0] = st[0]; s0[1] = st[1]; s0[2] = st[2]; s0[3] = st[3];
        s1[0] = st[4]; s1[1] = st[5]; s1[2] = st[6]; s1[3] = st[7];
        *(f32x4*)sp = s0;
        *(f32x4*)(sp + 4) = s1;
    }
    if (!do_z) return;

    // A-frag: this lane's own 8 dims, bf16-packed.
    u32x4 au;
    au[0] = cvt2bf(st[0], st[1]);
    au[1] = cvt2bf(st[2], st[3]);
    au[2] = cvt2bf(st[4], st[5]);
    au[3] = cvt2bf(st[6], st[7]);
    s16x8 af = as_s16x8(au);

    const u32x4* W1B = (const u32x4*)(ws + OFF_W1B);
    const float* B1 = ws + OFF_B1;
    f32x4 acc[8];
#pragma unroll
    for (int t = 0; t < 8; t++) {
        float bb = B1[t * 16 + col];
        acc[t][0] = bb; acc[t][1] = bb; acc[t][2] = bb; acc[t][3] = bb;
        acc[t] = __builtin_amdgcn_mfma_f32_16x16x32_bf16(af, as_s16x8(W1B[t * 64 + lane]), acc[t], 0, 0, 0);
    }

    // per-node stats: sum, sumsq, dot(z, w1last). rows m = quad*4+r.
    float s[4] = {0.f, 0.f, 0.f, 0.f}, q[4] = {0.f, 0.f, 0.f, 0.f}, d[4] = {0.f, 0.f, 0.f, 0.f};
    const float* W1L = ws + OFF_W1L;
#pragma unroll
    for (int t = 0; t < 8; t++) {
        float wl = W1L[t * 16 + col];
#pragma unroll
        for (int r = 0; r < 4; r++) {
            float z = acc[t][r];
            s[r] += z; q[r] = fmaf(z, z, q[r]); d[r] = fmaf(z, wl, d[r]);
        }
    }
#pragma unroll
    for (int r = 0; r < 4; r++) {
        float sr = row_reduce16(s[r]);
        float qr = row_reduce16(q[r]);
        float dr = row_reduce16(d[r]);
        if (col == 0) {
            f32x4 o; o[0] = sr; o[1] = qr; o[2] = dr; o[3] = 0.f;
            *(f32x4*)(ws + F_Z + (vbase + quad * 4 + r) * 68 + 64) = o;
        }
    }

    // z -> LDS transpose -> coalesced global (stride-68 rows).
    unsigned short* zw_ = zl[wv];
#pragma unroll
    for (int t = 0; t < 8; t++) {
        unsigned int p01 = cvt2bf(acc[t][0], acc[t][1]);
        unsigned int p23 = cvt2bf(acc[t][2], acc[t][3]);
        unsigned short* b = zw_ + quad * (4 * 136) + t * 16 + col;
        b[0]       = (unsigned short)p01;
        b[136]     = (unsigned short)(p01 >> 16);
        b[2 * 136] = (unsigned short)p23;
        b[3 * 136] = (unsigned short)(p23 >> 16);
    }
    unsigned int* zg = (unsigned int*)(ws + F_Z);
#pragma unroll
    for (int it = 0; it < 4; it++) {
        int byte = it * 1024 + lane * 16;
        int node = byte >> 8;
        int ko   = (byte & 255) >> 2;                // u32 index within row
        u32x4 val = *(const u32x4*)(zw_ + node * 136 + ((byte & 255) >> 1));
        *(u32x4*)(zg + (vbase + node) * 68L + ko) = val;
    }
}

// ---------------- edge kernel: source-ordered, closed-form LN1 + layer2 MFMA ----------------
// One wave per 16 consecutive source-CSR positions. Edges sharing a source
// share z[u] (~1-2 distinct 272B rows per wave -> cache-hot). NO LDS/barriers.
// msg scattered to dest-CSR slot (64B-aligned row per edge).
__launch_bounds__(256)
__global__ void edge_src_kernel(float* __restrict__ ws)
{
    const int lane = threadIdx.x & 63, wv = threadIdx.x >> 6;
    const int col = lane & 15, quad = lane >> 4;
    const long e_base = ((long)blockIdx.x * 4 + wv) * 16;
    const int epos = (int)e_base + col;

    u32x4 epk = *(const u32x4*)((const unsigned int*)(ws + F_EPK) + (long)epos * 4);
    const int u = (int)epk[0];
    union { unsigned int i; float f; } cc; cc.i = epk[1];
    const float ecv = cc.f;
    const int dsl = (int)epk[2];

    // closed-form LN1 stats from z-row tail
    const long zbase = (long)u * 68;
    f32x4 zst = *(const f32x4*)(ws + F_Z + zbase + 64);   // {sumz, sqz, dzw, 0}
    const float sw1 = ws[OFF_WSC], sqw1 = ws[OFF_WSC + 1];
    float sumh = fmaf(ecv, sw1, zst[0]);
    float sqh  = fmaf(ecv, fmaf(ecv, sqw1, 2.f * zst[2]), zst[1]);
    float mean = sumh * (1.f / HH);
    float var  = fmaxf(sqh * (1.f / HH) - mean * mean, 0.f);
    float inv  = rsqrtf(var + EPS);
    const float alpha = inv, beta = -mean * inv;

    // acc init = b2[msgdim]; msgdim = t2*16 + quad*4 + r
    f32x4 acc2[2];
#pragma unroll
    for (int t2 = 0; t2 < 2; t2++)
        acc2[t2] = *(const f32x4*)(ws + OFF_B2 + t2 * 16 + quad * 4);

    const unsigned int* zrow = (const unsigned int*)(ws + F_Z) + zbase;
    const u32x4* W2F = (const u32x4*)(ws + OFF_W2F);
#pragma unroll
    for (int ks = 0; ks < 4; ks++) {
        u32x4 zwv = *(const u32x4*)(zrow + ks * 16 + quad * 4);
        const int n0 = ks * 32 + quad * 8;
        f32x4 wlA = *(const f32x4*)(ws + OFF_W1L + n0);
        f32x4 wlB = *(const f32x4*)(ws + OFF_W1L + n0 + 4);
        f32x4 gA  = *(const f32x4*)(ws + OFF_G1  + n0);
        f32x4 gB  = *(const f32x4*)(ws + OFF_G1  + n0 + 4);
        f32x4 bA  = *(const f32x4*)(ws + OFF_BE1 + n0);
        f32x4 bB  = *(const f32x4*)(ws + OFF_BE1 + n0 + 4);
        float wl[8] = {wlA[0], wlA[1], wlA[2], wlA[3], wlB[0], wlB[1], wlB[2], wlB[3]};
        float gg[8] = {gA[0], gA[1], gA[2], gA[3], gB[0], gB[1], gB[2], gB[3]};
        float bb[8] = {bA[0], bA[1], bA[2], bA[3], bB[0], bB[1], bB[2], bB[3]};
        u32x4 hu;
#pragma unroll
        for (int w = 0; w < 4; w++) {
            float z0 = lo_bf(zwv[w]), z1 = hi_bf(zwv[w]);
            float h0 = fmaf(ecv, wl[2 * w],     z0);
            float h1 = fmaf(ecv, wl[2 * w + 1], z1);
            h0 = fmaf(h0, alpha, beta);          h1 = fmaf(h1, alpha, beta);
            h0 = fmaf(h0, gg[2 * w], bb[2 * w]); h1 = fmaf(h1, gg[2 * w + 1], bb[2 * w + 1]);
            h0 = fmaxf(h0, NEG * h0);            h1 = fmaxf(h1, NEG * h1);
            hu[w] = cvt2bf(h0, h1);
        }
        s16x8 hf = as_s16x8(hu);
        acc2[0] = __builtin_amdgcn_mfma_f32_16x16x32_bf16(as_s16x8(W2F[(ks * 2 + 0) * 64 + lane]), hf, acc2[0], 0, 0, 0);
        acc2[1] = __builtin_amdgcn_mfma_f32_16x16x32_bf16(as_s16x8(W2F[(ks * 2 + 1) * 64 + lane]), hf, acc2[1], 0, 0, 0);
    }

    // LN2: lane holds 8 of 32 msg dims for its edge (col); reduce across quads.
    float s2 = 0.f, q2 = 0.f;
#pragma unroll
    for (int t2 = 0; t2 < 2; t2++)
#pragma unroll
        for (int r = 0; r < 4; r++) { float vv = acc2[t2][r]; s2 += vv; q2 = fmaf(vv, vv, q2); }
    s2 += __shfl_xor(s2, 16); q2 += __shfl_xor(q2, 16);
    s2 += __shfl_xor(s2, 32); q2 += __shfl_xor(q2, 32);
    float mean2 = s2 * (1.f / SS);
    float var2  = fmaxf(q2 * (1.f / SS) - mean2 * mean2, 0.f);
    float inv2  = rsqrtf(var2 + EPS);
    const float a2 = inv2, b2c = -mean2 * inv2;

    // store: scattered 64B-aligned row at the edge's dest-CSR slot.
    unsigned int* dst = (unsigned int*)(ws + F_MSG) + (long)dsl * 16;
#pragma unroll
    for (int t2 = 0; t2 < 2; t2++) {
        f32x4 g = *(const f32x4*)(ws + OFF_G2  + t2 * 16 + quad * 4);
        f32x4 b = *(const f32x4*)(ws + OFF_BE2 + t2 * 16 + quad * 4);
        float m0 = fmaf(fmaf(acc2[t2][0], a2, b2c), g[0], b[0]);
        float m1 = fmaf(fmaf(acc2[t2][1], a2, b2c), g[1], b[1]);
        float m2 = fmaf(fmaf(acc2[t2][2], a2, b2c), g[2], b[2]);
        float m3 = fmaf(fmaf(acc2[t2][3], a2, b2c), g[3], b[3]);
        m0 = fmaxf(m0, NEG * m0); m1 = fmaxf(m1, NEG * m1);
        m2 = fmaxf(m2, NEG * m2); m3 = fmaxf(m3, NEG * m3);
        uint2 o; o.x = cvt2bf(m0, m1); o.y = cvt2bf(m2, m3);
        *(uint2*)(dst + t2 * 8 + quad * 2) = o;
    }
}

// graph segment-sum via CSR: 32 lanes per graph, no atomics.
__launch_bounds__(256)
__global__ void graph_gather_kernel(float* __restrict__ ws)
{
    int t = blockIdx.x * 256 + threadIdx.x;
    int g = t >> 5;
    if (g >= NG) return;
    int j = t & 31;
    const int* start = (const int*)(ws + F_GSTART);
    const int* list  = (const int*)(ws + F_GLIST);
    int s0 = start[g], s1 = start[g + 1];
    float acc = 0.f;
    for (int p = s0; p < s1; ++p)
        acc += ws[OFF_STATE + (long)list[p] * SS + j];
    ws[OFF_GS + (long)g * SS + j] = acc;
}

// ---------------- fallback (atomic) path ----------------
__launch_bounds__(256)
__global__ void edge_atomic_kernel(const int* __restrict__ nfrom, const int* __restrict__ nto,
                                   const void* __restrict__ ec, const void* __restrict__ g1raw,
                                   const float* __restrict__ cws, float* delta)
{
    int e = blockIdx.x * 256 + threadIdx.x;
    if (e >= NE) return;
    const float* state = cws + OFF_STATE;
    const float* W1T = cws + OFF_W1T;
    const float* B1  = cws + OFF_B1;
    const float* G1  = cws + OFF_G1;
    const float* BE1 = cws + OFF_BE1;
    const float* W2  = cws + OFF_W2;
    const float* B2  = cws + OFF_B2;
    const float* G2  = cws + OFF_G2;
    const float* BE2 = cws + OFF_BE2;
    int u = nfrom[e];
    float inp[33];
    const float4* srow = (const float4*)(state + (long)u * SS);
#pragma unroll
    for (int i = 0; i < 8; i++) {
        float4 v = srow[i];
        inp[i * 4 + 0] = v.x; inp[i * 4 + 1] = v.y;
        inp[i * 4 + 2] = v.z; inp[i * 4 + 3] = v.w;
    }
    inp[32] = ldf(ec, e, is_bf16(g1raw));
    float sum = 0.f, sq = 0.f;
    for (int k = 0; k < HH; k++) {
        const float* wr = W1T + k * 33;
        float a = B1[k];
#pragma unroll
        for (int i = 0; i < 33; i++) a = fmaf(inp[i], wr[i], a);
        sum += a; sq = fmaf(a, a, sq);
    }
    float mean = sum * (1.f / HH);
    float var  = sq * (1.f / HH) - mean * mean;
    float inv  = rsqrtf(var + EPS);
    float msg[SS];
#pragma unroll
    for (int j = 0; j < SS; j++) msg[j] = B2[j];
    for (int k = 0; k < HH; k++) {
        const float* wr = W1T + k * 33;
        float a = B1[k];
#pragma unroll
        for (int i = 0; i < 33; i++) a = fmaf(inp[i], wr[i], a);
        float hk = fmaf((a - mean) * inv, G1[k], BE1[k]);
        hk = hk >= 0.f ? hk : NEG * hk;
        const float* w2r = W2 + k * SS;
#pragma unroll
        for (int j = 0; j < SS; j++) msg[j] = fmaf(hk, w2r[j], msg[j]);
    }
    float s2 = 0.f, q2 = 0.f;
#pragma unroll
    for (int j = 0; j < SS; j++) { s2 += msg[j]; q2 = fmaf(msg[j], msg[j], q2); }
    float m2 = s2 * (1.f / SS);
    float v2 = q2 * (1.f / SS) - m2 * m2;
    float i2 = rsqrtf(v2 + EPS);
    int v = nto[e];
    float* drow = delta + (long)v * SS;
#pragma unroll
    for (int j = 0; j < SS; j++) {
        float mj = fmaf((msg[j] - m2) * i2, G2[j], BE2[j]);
        mj = mj >= 0.f ? mj : NEG * mj;
        atomicAdd(drow + j, mj);
    }
}

__global__ void update_kernel(float* ws)
{
    long idx = (long)blockIdx.x * blockDim.x + threadIdx.x;
    if (idx < (long)NN * SS) {
        ws[OFF_STATE + idx] += ws[OFF_DELTA + idx];
        ws[OFF_DELTA + idx] = 0.f;
    }
}

__global__ void graph_kernel(const int* __restrict__ gidx, float* ws)
{
    long idx = (long)blockIdx.x * blockDim.x + threadIdx.x;
    if (idx < (long)NN * SS) {
        int i = (int)(idx >> 5);
        int j = (int)(idx & 31);
        atomicAdd(&ws[OFF_GS + (long)gidx[i] * SS + j], ws[OFF_STATE + idx]);
    }
}

// ---------------- readout ----------------
__global__ void readout_kernel(const float* __restrict__ ws, const void* __restrict__ g1raw,
                               void* __restrict__ out)
{
    int g = blockIdx.x;
    int j = threadIdx.x;
    __shared__ float row[SS];
    __shared__ float buf[HH];
    __shared__ float p0[HH];
    __shared__ float p1[HH];

    const float* gs  = ws + OFF_GS;
    const float* Wo1 = ws + OFF_WO1;
    if (j < SS) row[j] = gs[(long)g * SS + j];
    __syncthreads();

    float a = ws[OFF_BO1 + j];
#pragma unroll
    for (int i = 0; i < SS; i++) a = fmaf(row[i], Wo1[i * HH + j], a);
    buf[j] = a;
    __syncthreads();

    float sum = 0.f, sq = 0.f;
    for (int i = 0; i < HH; i++) { float x = buf[i]; sum += x; sq = fmaf(x, x, sq); }
    float mean = sum * (1.f / HH);
    float var  = sq * (1.f / HH) - mean * mean;
    float inv  = rsqrtf(var + EPS);
    float h = fmaf((a - mean) * inv, ws[OFF_GO + j], ws[OFF_BEO + j]);
    h = h >= 0.f ? h : NEG * h;

    p0[j] = h * ws[OFF_WO2 + j * 2 + 0];
    p1[j] = h * ws[OFF_WO2 + j * 2 + 1];
    __syncthreads();

    if (j == 0) {
        float e0 = ws[OFF_BO2 + 0], e1 = ws[OFF_BO2 + 1];
        for (int i = 0; i < HH; i++) { e0 += p0[i]; e1 += p1[i]; }
        float sp = (e1 > 20.f) ? e1 : log1pf(expf(e1));
        if (is_bf16(g1raw)) {
            __hip_bfloat16* o = (__hip_bfloat16*)out;
            o[g * 2 + 0] = __float2bfloat16(e0);
            o[g * 2 + 1] = __float2bfloat16(sp);
        } else {
            float* o = (float*)out;
            o[g * 2 + 0] = e0;
            o[g * 2 + 1] = sp;
        }
    }
}

extern "C" void kernel_launch(void* const* d_in, const int* in_sizes, int n_in,
                              void* d_out, int out_size, void* d_ws, size_t ws_size,
                              hipStream_t stream)
{
    const int* nfrom = (const int*)d_in[0];
    const int* nto   = (const int*)d_in[1];
    const void* ec   = d_in[2];
    const int* gidx  = (const int*)d_in[3];
    const void* W1  = d_in[6];
    const void* b1  = d_in[7];
    const void* g1  = d_in[8];
    const void* be1 = d_in[9];
    const void* W2  = d_in[10];
    const void* b2  = d_in[11];
    const void* g2  = d_in[12];
    const void* be2 = d_in[13];
    const void* Wo1 = d_in[14];
    const void* bo1 = d_in[15];
    const void* go  = d_in[16];
    const void* beo = d_in[17];
    const void* Wo2 = d_in[18];
    const void* bo2 = d_in[19];

    float* ws = (float*)d_ws;
    if (ws_size < (size_t)WS_FALLBACK * sizeof(float)) return;
    const bool gather = ws_size >= (size_t)WS_TOTAL * sizeof(float);

    const int nsBlocks = (int)(((long)NN * SS + 255) / 256);   // 12500
    const int eBlocks  = (NE + 255) / 256;                     // 6250
    const int efBlocks = NE / 64;                              // 25000 (4 waves x 16 edges)
    const int ndBlocks = (NN / 16 + 3) / 4;                    // 1563  (4 waves x 16 nodes)
    const int nBlocks1 = (NN + 255) / 256;                     // 391

    prep_kernel<<<nsBlocks, 256, 0, stream>>>(W1, b1, g1, be1, W2, b2, g2, be2,
                                              Wo1, bo1, go, beo, Wo2, bo2, ws);
    if (gather) {
        hist2_kernel<<<eBlocks, 256, 0, stream>>>(nto, nfrom, ws);
        scan1_kernel<<<NBLK_N, 256, 0, stream>>>(ws, F_DEG, F_START);
        scan2_kernel<<<1, 64, 0, stream>>>(ws);
        scan3_kernel<<<NBLK_N, 256, 0, stream>>>(ws, F_START, F_CURSOR);
        fill1_kernel<<<eBlocks, 256, 0, stream>>>(nto, ws);
        scan1_kernel<<<NBLK_N, 256, 0, stream>>>(ws, F_SDEG, F_SSTART);
        scan2_kernel<<<1, 64, 0, stream>>>(ws);
        scan3_kernel<<<NBLK_N, 256, 0, stream>>>(ws, F_SSTART, F_SCUR);
        fill2_kernel<<<eBlocks, 256, 0, stream>>>(nfrom, ec, g1, ws);
        ghist_kernel<<<nBlocks1, 256, 0, stream>>>(gidx, ws);
        gscan_kernel<<<1, 1024, 0, stream>>>(ws);
        gfill_kernel<<<nBlocks1, 256, 0, stream>>>(gidx, ws);
        // round 0: state = 0 -> z0 + stats (no gather)
        node_kernel<<<ndBlocks, 256, 0, stream>>>(ws, 0, 1);
        for (int r = 0; r < ROUNDS; r++) {
            edge_src_kernel<<<efBlocks, 256, 0, stream>>>(ws);
            node_kernel    <<<ndBlocks, 256, 0, stream>>>(ws, 1, (r < ROUNDS - 1) ? 1 : 0);
        }
        graph_gather_kernel<<<(NG * 32 + 255) / 256, 256, 0, stream>>>(ws);
    } else {
        for (int r = 0; r < ROUNDS; r++) {
            edge_atomic_kernel<<<eBlocks, 256, 0, stream>>>(nfrom, nto, ec, g1, ws, ws + OFF_DELTA);
            update_kernel<<<nsBlocks, 256, 0, stream>>>(ws);
        }
        graph_kernel<<<nsBlocks, 256, 0, stream>>>(gidx, ws);
    }
    readout_kernel<<<NG, HH, 0, stream>>>(ws, g1, (void*)d_out);
}